// Round 2
// baseline (1022.624 us; speedup 1.0000x reference)
//
#include <hip/hip_runtime.h>
#include <math.h>

#define TT 35
#define DD 10
#define HD 400
#define WD 352
#define CIN 7
#define U1 16
#define U2 32
#define EPSV 1e-5f

// ws float layout
#define WS_A1 0
#define WS_B1 16
#define WS_A2 32
#define WS_B2 64
#define WS_SUM1 256
#define WS_SSQ1 768
#define WS_SUM2 1280
#define WS_SSQ2 3328
#define NC1 32
#define NC2 64
#define WS_ZERO_FLOATS 5376

// ---------------------------------------------------------------------------
// Kernel 1: layer-1 BN statistics. h1 = relu(x @ w1 + b1); accumulate
// per-channel sum and sumsq over all K*T points.
// ---------------------------------------------------------------------------
__global__ __launch_bounds__(256) void k_stats1(
    const float* __restrict__ feat, const float* __restrict__ w1,
    const float* __restrict__ b1, float* __restrict__ ws, int P) {
  __shared__ float s_w1[CIN * U1];
  __shared__ float s_b1[U1];
  __shared__ float s_red[4][2 * U1];

  int tid = threadIdx.x;
  if (tid < CIN * U1) s_w1[tid] = w1[tid];
  if (tid < U1) s_b1[tid] = b1[tid];
  __syncthreads();

  float sum[U1], ssq[U1];
#pragma unroll
  for (int u = 0; u < U1; ++u) { sum[u] = 0.f; ssq[u] = 0.f; }

  int stride = gridDim.x * blockDim.x;
  for (int p = blockIdx.x * blockDim.x + tid; p < P; p += stride) {
    const float* f = feat + (size_t)p * CIN;
    float x[CIN];
#pragma unroll
    for (int c = 0; c < CIN; ++c) x[c] = f[c];
#pragma unroll
    for (int u = 0; u < U1; ++u) {
      float acc = s_b1[u];
#pragma unroll
      for (int c = 0; c < CIN; ++c) acc += x[c] * s_w1[c * U1 + u];
      float h = fmaxf(acc, 0.f);
      sum[u] += h;
      ssq[u] += h * h;
    }
  }

  int lane = tid & 63, wv = tid >> 6;
#pragma unroll
  for (int u = 0; u < U1; ++u) {
    float s = sum[u], q = ssq[u];
    for (int off = 32; off; off >>= 1) {
      s += __shfl_down(s, off);
      q += __shfl_down(q, off);
    }
    if (lane == 0) { s_red[wv][u] = s; s_red[wv][U1 + u] = q; }
  }
  __syncthreads();
  if (tid < 2 * U1) {
    float tot = s_red[0][tid] + s_red[1][tid] + s_red[2][tid] + s_red[3][tid];
    int copy = blockIdx.x & (NC1 - 1);
    int u = tid & (U1 - 1);
    int base = (tid < U1) ? WS_SUM1 : WS_SSQ1;
    atomicAdd(&ws[base + copy * U1 + u], tot);
  }
}

__global__ void k_fin1(const float* __restrict__ gamma,
                       const float* __restrict__ beta, float* __restrict__ ws,
                       float invN) {
  int u = threadIdx.x;  // U1 threads
  float s = 0.f, q = 0.f;
  for (int c = 0; c < NC1; ++c) {
    s += ws[WS_SUM1 + c * U1 + u];
    q += ws[WS_SSQ1 + c * U1 + u];
  }
  float mean = s * invN;
  float var = q * invN - mean * mean;
  float istd = 1.0f / sqrtf(var + EPSV);
  float A = gamma[u] * istd;
  ws[WS_A1 + u] = A;
  ws[WS_B1 + u] = beta[u] - mean * A;
}

__global__ void k_fin2(const float* __restrict__ gamma,
                       const float* __restrict__ beta, float* __restrict__ ws,
                       float invN) {
  int u = threadIdx.x;  // U2 threads
  float s = 0.f, q = 0.f;
  for (int c = 0; c < NC2; ++c) {
    s += ws[WS_SUM2 + c * U2 + u];
    q += ws[WS_SSQ2 + c * U2 + u];
  }
  float mean = s * invN;
  float var = q * invN - mean * mean;
  float istd = 1.0f / sqrtf(var + EPSV);
  float A = gamma[u] * istd;
  ws[WS_A2 + u] = A;
  ws[WS_B2 + u] = beta[u] - mean * A;
}

// ---------------------------------------------------------------------------
// Main VFE kernel: one wave per voxel, 4 voxels per 256-thread block.
// FINAL=false: recompute h1 -> cat -> h2, accumulate layer-2 stats.
// FINAL=true : full recompute, normalize h2, agg2, voxelwise max, scatter.
// ---------------------------------------------------------------------------
template <bool FINAL>
__global__ __launch_bounds__(256) void k_vfe(
    const float* __restrict__ feat, const float* __restrict__ w1,
    const float* __restrict__ b1, const float* __restrict__ w2,
    const float* __restrict__ b2, const int* __restrict__ coord,
    float* __restrict__ ws, float* __restrict__ out, int K) {
  __shared__ float s_w1t[U1][9];                       // transposed, pad->no conflicts
  __shared__ __align__(16) float s_w2t[U2 * U2];       // s_w2t[u*32+c] = w2[c][u]
  __shared__ float s_b1[U1], s_A1[U1], s_B1[U1];
  __shared__ float s_b2[U2], s_A2[U2], s_B2[U2];
  __shared__ float s_feat[4][TT * 9];                  // [t*9+c]; [t*9+7] = mask
  __shared__ __align__(16) float s_cat[4][TT][U2];
  __shared__ float s_agg[4][U1];
  __shared__ float s_red[4][2 * U2];
  __shared__ __align__(16) float s_h2[FINAL ? 4 : 1][TT][U2];

  int tid = threadIdx.x;
  int lane = tid & 63, wv = tid >> 6;
  int v = blockIdx.x * 4 + wv;
  bool active = (v < K);

  // ---- block-cooperative weight / param staging ----
  if (tid < CIN * U1) {
    int u = tid / CIN, c = tid % CIN;
    s_w1t[u][c] = w1[c * U1 + u];
  }
  for (int i = tid; i < U2 * U2; i += 256) {
    int u = i >> 5, c = i & 31;
    s_w2t[i] = w2[c * U2 + u];
  }
  if (tid < U1) {
    s_b1[tid] = b1[tid];
    s_A1[tid] = ws[WS_A1 + tid];
    s_B1[tid] = ws[WS_B1 + tid];
  }
  if (tid < U2) {
    s_b2[tid] = b2[tid];
    s_A2[tid] = ws[WS_A2 + tid];
    s_B2[tid] = ws[WS_B2 + tid];
  }
  __syncthreads();

  // ---- stage 0: load feature tile, compute mask ----
  if (active) {
    const float* fv = feat + (size_t)v * TT * CIN;
    for (int i = lane; i < TT * CIN; i += 64) {
      int t = i / CIN, c = i % CIN;
      s_feat[wv][t * 9 + c] = fv[i];
    }
  }
  __syncthreads();
  if (active && lane < TT) {
    float m = s_feat[wv][lane * 9 + 0];
#pragma unroll
    for (int c = 1; c < CIN; ++c) m = fmaxf(m, s_feat[wv][lane * 9 + c]);
    s_feat[wv][lane * 9 + 7] = (m != 0.f) ? 1.f : 0.f;
  }
  __syncthreads();

  // ---- stage 1: h1n = A1*relu(x@w1+b1)+B1  (unmasked) ----
  if (active) {
    for (int i = lane; i < TT * U1; i += 64) {
      int t = i >> 4, u = i & 15;
      float acc = s_b1[u];
#pragma unroll
      for (int c = 0; c < CIN; ++c) acc += s_feat[wv][t * 9 + c] * s_w1t[u][c];
      float h = fmaxf(acc, 0.f);
      s_cat[wv][t][u] = s_A1[u] * h + s_B1[u];
    }
  }
  __syncthreads();
  // agg1 = max over t of (unmasked) h1n
  if (active && lane < U1) {
    float m = s_cat[wv][0][lane];
    for (int t = 1; t < TT; ++t) m = fmaxf(m, s_cat[wv][t][lane]);
    s_agg[wv][lane] = m;
  }
  __syncthreads();
  // apply mask, fill agg half of cat
  if (active) {
    for (int i = lane; i < TT * U1; i += 64) {
      int t = i >> 4, u = i & 15;
      float mk = s_feat[wv][t * 9 + 7];
      s_cat[wv][t][u] *= mk;
      s_cat[wv][t][U1 + u] = s_agg[wv][u] * mk;
    }
  }
  __syncthreads();

  // ---- stage 2: matmul2. lane owns output channel u = lane&31, row pairs. ----
  int u = lane & 31;
  int th = lane >> 5;  // 0 or 1: even/odd t rows
  float rw2[U2];
#pragma unroll
  for (int c4 = 0; c4 < 8; ++c4) {
    float4 v4 = *(const float4*)&s_w2t[u * U2 + 4 * c4];
    rw2[4 * c4 + 0] = v4.x;
    rw2[4 * c4 + 1] = v4.y;
    rw2[4 * c4 + 2] = v4.z;
    rw2[4 * c4 + 3] = v4.w;
  }
  float b2u = s_b2[u], A2u = s_A2[u], B2u = s_B2[u];
  float sum2 = 0.f, ssq2 = 0.f;
  if (active) {
    for (int t = th; t < TT; t += 2) {
      float acc = b2u;
      const float4* cr = (const float4*)&s_cat[wv][t][0];
#pragma unroll
      for (int c4 = 0; c4 < 8; ++c4) {
        float4 v4 = cr[c4];
        acc += v4.x * rw2[4 * c4] + v4.y * rw2[4 * c4 + 1] +
               v4.z * rw2[4 * c4 + 2] + v4.w * rw2[4 * c4 + 3];
      }
      float h = fmaxf(acc, 0.f);
      if (FINAL) {
        s_h2[wv][t][u] = A2u * h + B2u;
      } else {
        sum2 += h;
        ssq2 += h * h;
      }
    }
  }

  if (!FINAL) {
    // combine lane and lane+32 (same channel), then cross-wave via LDS
    float o1 = __shfl_down(sum2, 32);
    float o2 = __shfl_down(ssq2, 32);
    if (lane < 32) {
      s_red[wv][lane] = sum2 + o1;
      s_red[wv][U2 + lane] = ssq2 + o2;
    }
    __syncthreads();
    if (tid < 2 * U2) {
      float tot = s_red[0][tid] + s_red[1][tid] + s_red[2][tid] + s_red[3][tid];
      int copy = blockIdx.x & (NC2 - 1);
      int ch = tid & (U2 - 1);
      int base = (tid < U2) ? WS_SUM2 : WS_SSQ2;
      atomicAdd(&ws[base + copy * U2 + ch], tot);
    }
  } else {
    __syncthreads();
    // agg2 = max over t of (unmasked) h2n; lanes 0..31 compute, broadcast up
    float aggv = 0.f;
    if (active && lane < U2) {
      float m = s_h2[wv][0][lane];
      for (int t = 1; t < TT; ++t) m = fmaxf(m, s_h2[wv][t][lane]);
      aggv = m;
    }
    float aggb = __shfl(aggv, lane & 31);
    // voxelwise[c] = max over t of cat2[t][c] * mask[t]
    if (active) {
      int c = lane;  // 0..63
      float vox = -INFINITY;
      for (int t = 0; t < TT; ++t) {
        float mk = s_feat[wv][t * 9 + 7];
        float val = (c < U2) ? s_h2[wv][t][c] : aggb;
        vox = fmaxf(vox, val * mk);
      }
      const int4 cd = *(const int4*)&coord[4 * v];
      long base =
          ((((long)cd.x * DD + cd.y) * HD + cd.z) * WD + cd.w) * 64;
      atomicAdd(&out[base + c], vox);
    }
  }
}

// ---------------------------------------------------------------------------
extern "C" void kernel_launch(void* const* d_in, const int* in_sizes, int n_in,
                              void* d_out, int out_size, void* d_ws,
                              size_t ws_size, hipStream_t stream) {
  const float* feat = (const float*)d_in[0];
  const float* w1 = (const float*)d_in[1];
  const float* b1 = (const float*)d_in[2];
  const float* g1 = (const float*)d_in[3];
  const float* be1 = (const float*)d_in[4];
  const float* w2 = (const float*)d_in[5];
  const float* b2 = (const float*)d_in[6];
  const float* g2 = (const float*)d_in[7];
  const float* be2 = (const float*)d_in[8];
  const int* coord = (const int*)d_in[9];
  float* out = (float*)d_out;
  float* ws = (float*)d_ws;

  int K = in_sizes[0] / (TT * CIN);
  int P = K * TT;
  float invN = 1.0f / (float)P;

  (void)hipMemsetAsync(d_out, 0, (size_t)out_size * sizeof(float), stream);
  (void)hipMemsetAsync(d_ws, 0, WS_ZERO_FLOATS * sizeof(float), stream);

  k_stats1<<<512, 256, 0, stream>>>(feat, w1, b1, ws, P);
  k_fin1<<<1, U1, 0, stream>>>(g1, be1, ws, invN);

  int vb = (K + 3) / 4;
  k_vfe<false><<<vb, 256, 0, stream>>>(feat, w1, b1, w2, b2, nullptr, ws,
                                       nullptr, K);
  k_fin2<<<1, U2, 0, stream>>>(g2, be2, ws, invN);
  k_vfe<true><<<vb, 256, 0, stream>>>(feat, w1, b1, w2, b2, coord, ws, out, K);
}

// Round 3
// 915.459 us; speedup vs baseline: 1.1171x; 1.1171x over previous
//
#include <hip/hip_runtime.h>
#include <math.h>

#define TT 35
#define DD 10
#define HD 400
#define WD 352
#define CIN 7
#define U1 16
#define U2 32
#define EPSV 1e-5f

// ws float layout
#define WS_A1 0
#define WS_B1 16
#define WS_A2 32
#define WS_B2 64
#define WS_SUM1 256
#define WS_SSQ1 768
#define WS_SUM2 1280
#define WS_SSQ2 3328
#define NC1 32
#define NC2 64
#define WS_ZERO_FLOATS 5376
#define WS_H2_OFF 8192  // float offset of stored h2 (pre-BN, post-relu)

// ---------------------------------------------------------------------------
// Layer-1 BN statistics. h1 = relu(x @ w1 + b1); accumulate per-channel
// sum and sumsq over all K*T points.
// ---------------------------------------------------------------------------
__global__ __launch_bounds__(256) void k_stats1(
    const float* __restrict__ feat, const float* __restrict__ w1,
    const float* __restrict__ b1, float* __restrict__ ws, int P) {
  __shared__ float s_w1[CIN * U1];
  __shared__ float s_b1[U1];
  __shared__ float s_red[4][2 * U1];

  int tid = threadIdx.x;
  if (tid < CIN * U1) s_w1[tid] = w1[tid];
  if (tid < U1) s_b1[tid] = b1[tid];
  __syncthreads();

  float sum[U1], ssq[U1];
#pragma unroll
  for (int u = 0; u < U1; ++u) { sum[u] = 0.f; ssq[u] = 0.f; }

  int stride = gridDim.x * blockDim.x;
  for (int p = blockIdx.x * blockDim.x + tid; p < P; p += stride) {
    const float* f = feat + (size_t)p * CIN;
    float x[CIN];
#pragma unroll
    for (int c = 0; c < CIN; ++c) x[c] = f[c];
#pragma unroll
    for (int u = 0; u < U1; ++u) {
      float acc = s_b1[u];
#pragma unroll
      for (int c = 0; c < CIN; ++c) acc += x[c] * s_w1[c * U1 + u];
      float h = fmaxf(acc, 0.f);
      sum[u] += h;
      ssq[u] += h * h;
    }
  }

  int lane = tid & 63, wv = tid >> 6;
#pragma unroll
  for (int u = 0; u < U1; ++u) {
    float s = sum[u], q = ssq[u];
    for (int off = 32; off; off >>= 1) {
      s += __shfl_down(s, off);
      q += __shfl_down(q, off);
    }
    if (lane == 0) { s_red[wv][u] = s; s_red[wv][U1 + u] = q; }
  }
  __syncthreads();
  if (tid < 2 * U1) {
    float tot = s_red[0][tid] + s_red[1][tid] + s_red[2][tid] + s_red[3][tid];
    int copy = blockIdx.x & (NC1 - 1);
    int u = tid & (U1 - 1);
    int base = (tid < U1) ? WS_SUM1 : WS_SSQ1;
    atomicAdd(&ws[base + copy * U1 + u], tot);
  }
}

__global__ void k_fin1(const float* __restrict__ gamma,
                       const float* __restrict__ beta, float* __restrict__ ws,
                       float invN) {
  int u = threadIdx.x;  // U1 threads
  float s = 0.f, q = 0.f;
  for (int c = 0; c < NC1; ++c) {
    s += ws[WS_SUM1 + c * U1 + u];
    q += ws[WS_SSQ1 + c * U1 + u];
  }
  float mean = s * invN;
  float var = q * invN - mean * mean;
  float istd = 1.0f / sqrtf(var + EPSV);
  float A = gamma[u] * istd;
  ws[WS_A1 + u] = A;
  ws[WS_B1 + u] = beta[u] - mean * A;
}

__global__ void k_fin2(const float* __restrict__ gamma,
                       const float* __restrict__ beta, float* __restrict__ ws,
                       float invN) {
  int u = threadIdx.x;  // U2 threads
  float s = 0.f, q = 0.f;
  for (int c = 0; c < NC2; ++c) {
    s += ws[WS_SUM2 + c * U2 + u];
    q += ws[WS_SSQ2 + c * U2 + u];
  }
  float mean = s * invN;
  float var = q * invN - mean * mean;
  float istd = 1.0f / sqrtf(var + EPSV);
  float A = gamma[u] * istd;
  ws[WS_A2 + u] = A;
  ws[WS_B2 + u] = beta[u] - mean * A;
}

// ---------------------------------------------------------------------------
// Stats pass: one wave per voxel, 4 voxels per 256-thread block.
// Recomputes h1 -> cat -> h2 (pre-BN), accumulates layer-2 stats.
// If STORE: also writes h2 + mask to workspace for the slim final pass.
// Epilogue: grid-stride zero of the output tensor (fire-and-forget stores
// AFTER the last barrier so they drain while other blocks compute).
// ---------------------------------------------------------------------------
template <bool STORE>
__global__ __launch_bounds__(256) void k_vfe2(
    const float* __restrict__ feat, const float* __restrict__ w1,
    const float* __restrict__ b1, const float* __restrict__ w2,
    const float* __restrict__ b2, float* __restrict__ ws,
    float* __restrict__ h2g, float* __restrict__ maskg,
    float4* __restrict__ out4, long n4, int K) {
  __shared__ float s_w1t[U1][9];
  __shared__ __align__(16) float s_w2t[U2 * U2];  // s_w2t[u*32+c] = w2[c][u]
  __shared__ float s_b1[U1], s_A1[U1], s_B1[U1];
  __shared__ float s_b2[U2];
  __shared__ float s_feat[4][TT * 9];             // [t*9+c]; [t*9+7] = mask
  __shared__ __align__(16) float s_cat[4][TT][U2];
  __shared__ float s_agg[4][U1];
  __shared__ float s_red[4][2 * U2];

  int tid = threadIdx.x;
  int lane = tid & 63, wv = tid >> 6;
  int v = blockIdx.x * 4 + wv;
  bool active = (v < K);

  // ---- block-cooperative weight / param staging ----
  if (tid < CIN * U1) {
    int u = tid / CIN, c = tid % CIN;
    s_w1t[u][c] = w1[c * U1 + u];
  }
  for (int i = tid; i < U2 * U2; i += 256) {
    int u = i >> 5, c = i & 31;
    s_w2t[i] = w2[c * U2 + u];
  }
  if (tid < U1) {
    s_b1[tid] = b1[tid];
    s_A1[tid] = ws[WS_A1 + tid];
    s_B1[tid] = ws[WS_B1 + tid];
  }
  if (tid < U2) s_b2[tid] = b2[tid];
  __syncthreads();

  // ---- stage 0: load feature tile, compute mask ----
  if (active) {
    const float* fv = feat + (size_t)v * TT * CIN;
    for (int i = lane; i < TT * CIN; i += 64) {
      int t = i / CIN, c = i % CIN;
      s_feat[wv][t * 9 + c] = fv[i];
    }
  }
  __syncthreads();
  if (active && lane < TT) {
    float m = s_feat[wv][lane * 9 + 0];
#pragma unroll
    for (int c = 1; c < CIN; ++c) m = fmaxf(m, s_feat[wv][lane * 9 + c]);
    float mk = (m != 0.f) ? 1.f : 0.f;
    s_feat[wv][lane * 9 + 7] = mk;
    if (STORE) maskg[(size_t)v * TT + lane] = mk;
  }
  __syncthreads();

  // ---- stage 1: h1n = A1*relu(x@w1+b1)+B1 (unmasked) ----
  if (active) {
    for (int i = lane; i < TT * U1; i += 64) {
      int t = i >> 4, u = i & 15;
      float acc = s_b1[u];
#pragma unroll
      for (int c = 0; c < CIN; ++c) acc += s_feat[wv][t * 9 + c] * s_w1t[u][c];
      float h = fmaxf(acc, 0.f);
      s_cat[wv][t][u] = s_A1[u] * h + s_B1[u];
    }
  }
  __syncthreads();
  if (active && lane < U1) {
    float m = s_cat[wv][0][lane];
    for (int t = 1; t < TT; ++t) m = fmaxf(m, s_cat[wv][t][lane]);
    s_agg[wv][lane] = m;
  }
  __syncthreads();
  if (active) {
    for (int i = lane; i < TT * U1; i += 64) {
      int t = i >> 4, u = i & 15;
      float mk = s_feat[wv][t * 9 + 7];
      s_cat[wv][t][u] *= mk;
      s_cat[wv][t][U1 + u] = s_agg[wv][u] * mk;
    }
  }
  __syncthreads();

  // ---- stage 2: matmul2; lane owns channel u=lane&31, t strided by 2 ----
  int u = lane & 31;
  int th = lane >> 5;
  float rw2[U2];
#pragma unroll
  for (int c4 = 0; c4 < 8; ++c4) {
    float4 v4 = *(const float4*)&s_w2t[u * U2 + 4 * c4];
    rw2[4 * c4 + 0] = v4.x;
    rw2[4 * c4 + 1] = v4.y;
    rw2[4 * c4 + 2] = v4.z;
    rw2[4 * c4 + 3] = v4.w;
  }
  float b2u = s_b2[u];
  float sum2 = 0.f, ssq2 = 0.f;
  if (active) {
    for (int t = th; t < TT; t += 2) {
      float acc = b2u;
      const float4* cr = (const float4*)&s_cat[wv][t][0];
#pragma unroll
      for (int c4 = 0; c4 < 8; ++c4) {
        float4 v4 = cr[c4];
        acc += v4.x * rw2[4 * c4] + v4.y * rw2[4 * c4 + 1] +
               v4.z * rw2[4 * c4 + 2] + v4.w * rw2[4 * c4 + 3];
      }
      float h = fmaxf(acc, 0.f);
      if (STORE) h2g[((size_t)v * TT + t) * U2 + u] = h;
      sum2 += h;
      ssq2 += h * h;
    }
  }

  // ---- layer-2 stats reduction ----
  float o1 = __shfl_down(sum2, 32);
  float o2 = __shfl_down(ssq2, 32);
  if (lane < 32) {
    s_red[wv][lane] = sum2 + o1;
    s_red[wv][U2 + lane] = ssq2 + o2;
  }
  __syncthreads();
  if (tid < 2 * U2) {
    float tot = s_red[0][tid] + s_red[1][tid] + s_red[2][tid] + s_red[3][tid];
    int copy = blockIdx.x & (NC2 - 1);
    int ch = tid & (U2 - 1);
    int base = (tid < U2) ? WS_SUM2 : WS_SSQ2;
    atomicAdd(&ws[base + copy * U2 + ch], tot);
  }

  // ---- epilogue: zero the output tensor (no barrier after -> overlaps) ----
  long gtid = (long)blockIdx.x * 256 + tid;
  long gstride = (long)gridDim.x * 256;
  float4 z = make_float4(0.f, 0.f, 0.f, 0.f);
  for (long i = gtid; i < n4; i += gstride) out4[i] = z;
}

// ---------------------------------------------------------------------------
// Slim final pass (STORE path): load stored h2 + mask, apply BN affine,
// agg2 + voxelwise max in registers, scatter-add.
// ---------------------------------------------------------------------------
__global__ __launch_bounds__(256) void k_final(
    const float* __restrict__ h2g, const float* __restrict__ maskg,
    const float* __restrict__ ws, const int* __restrict__ coord,
    float* __restrict__ out, int K) {
  int tid = threadIdx.x;
  int lane = tid & 63, wv = tid >> 6;
  int v = blockIdx.x * 4 + wv;
  if (v >= K) return;
  int ch = lane & 31;
  float A2 = ws[WS_A2 + ch], B2 = ws[WS_B2 + ch];
  const float* hrow = h2g + (size_t)v * TT * U2 + ch;
  const float* mrow = maskg + (size_t)v * TT;
  float agg = -INFINITY, vox = -INFINITY;
  bool any1 = false, any0 = false;
#pragma unroll 5
  for (int t = 0; t < TT; ++t) {
    float h = hrow[(size_t)t * U2];
    float mk = mrow[t];
    float hn = A2 * h + B2;
    agg = fmaxf(agg, hn);
    vox = fmaxf(vox, hn * mk);
    any1 |= (mk != 0.f);
    any0 |= (mk == 0.f);
  }
  if (lane >= 32) vox = any1 ? (any0 ? fmaxf(agg, 0.f) : agg) : 0.f;
  const int4 cd = *(const int4*)&coord[4 * v];
  long base = ((((long)cd.x * DD + cd.y) * HD + cd.z) * WD + cd.w) * 64;
  atomicAdd(&out[base + lane], vox);
}

// ---------------------------------------------------------------------------
// Fallback final pass (small ws): full recompute + finalize + scatter.
// ---------------------------------------------------------------------------
__global__ __launch_bounds__(256) void k_vfe_final_recompute(
    const float* __restrict__ feat, const float* __restrict__ w1,
    const float* __restrict__ b1, const float* __restrict__ w2,
    const float* __restrict__ b2, const int* __restrict__ coord,
    float* __restrict__ ws, float* __restrict__ out, int K) {
  __shared__ float s_w1t[U1][9];
  __shared__ __align__(16) float s_w2t[U2 * U2];
  __shared__ float s_b1[U1], s_A1[U1], s_B1[U1];
  __shared__ float s_b2[U2], s_A2[U2], s_B2[U2];
  __shared__ float s_feat[4][TT * 9];
  __shared__ __align__(16) float s_cat[4][TT][U2];
  __shared__ float s_agg[4][U1];
  __shared__ __align__(16) float s_h2[4][TT][U2];

  int tid = threadIdx.x;
  int lane = tid & 63, wv = tid >> 6;
  int v = blockIdx.x * 4 + wv;
  bool active = (v < K);

  if (tid < CIN * U1) {
    int u = tid / CIN, c = tid % CIN;
    s_w1t[u][c] = w1[c * U1 + u];
  }
  for (int i = tid; i < U2 * U2; i += 256) {
    int u = i >> 5, c = i & 31;
    s_w2t[i] = w2[c * U2 + u];
  }
  if (tid < U1) {
    s_b1[tid] = b1[tid];
    s_A1[tid] = ws[WS_A1 + tid];
    s_B1[tid] = ws[WS_B1 + tid];
  }
  if (tid < U2) {
    s_b2[tid] = b2[tid];
    s_A2[tid] = ws[WS_A2 + tid];
    s_B2[tid] = ws[WS_B2 + tid];
  }
  __syncthreads();

  if (active) {
    const float* fv = feat + (size_t)v * TT * CIN;
    for (int i = lane; i < TT * CIN; i += 64) {
      int t = i / CIN, c = i % CIN;
      s_feat[wv][t * 9 + c] = fv[i];
    }
  }
  __syncthreads();
  if (active && lane < TT) {
    float m = s_feat[wv][lane * 9 + 0];
#pragma unroll
    for (int c = 1; c < CIN; ++c) m = fmaxf(m, s_feat[wv][lane * 9 + c]);
    s_feat[wv][lane * 9 + 7] = (m != 0.f) ? 1.f : 0.f;
  }
  __syncthreads();

  if (active) {
    for (int i = lane; i < TT * U1; i += 64) {
      int t = i >> 4, u = i & 15;
      float acc = s_b1[u];
#pragma unroll
      for (int c = 0; c < CIN; ++c) acc += s_feat[wv][t * 9 + c] * s_w1t[u][c];
      float h = fmaxf(acc, 0.f);
      s_cat[wv][t][u] = s_A1[u] * h + s_B1[u];
    }
  }
  __syncthreads();
  if (active && lane < U1) {
    float m = s_cat[wv][0][lane];
    for (int t = 1; t < TT; ++t) m = fmaxf(m, s_cat[wv][t][lane]);
    s_agg[wv][lane] = m;
  }
  __syncthreads();
  if (active) {
    for (int i = lane; i < TT * U1; i += 64) {
      int t = i >> 4, u = i & 15;
      float mk = s_feat[wv][t * 9 + 7];
      s_cat[wv][t][u] *= mk;
      s_cat[wv][t][U1 + u] = s_agg[wv][u] * mk;
    }
  }
  __syncthreads();

  int u = lane & 31;
  int th = lane >> 5;
  float rw2[U2];
#pragma unroll
  for (int c4 = 0; c4 < 8; ++c4) {
    float4 v4 = *(const float4*)&s_w2t[u * U2 + 4 * c4];
    rw2[4 * c4 + 0] = v4.x;
    rw2[4 * c4 + 1] = v4.y;
    rw2[4 * c4 + 2] = v4.z;
    rw2[4 * c4 + 3] = v4.w;
  }
  float b2u = s_b2[u], A2u = s_A2[u], B2u = s_B2[u];
  if (active) {
    for (int t = th; t < TT; t += 2) {
      float acc = b2u;
      const float4* cr = (const float4*)&s_cat[wv][t][0];
#pragma unroll
      for (int c4 = 0; c4 < 8; ++c4) {
        float4 v4 = cr[c4];
        acc += v4.x * rw2[4 * c4] + v4.y * rw2[4 * c4 + 1] +
               v4.z * rw2[4 * c4 + 2] + v4.w * rw2[4 * c4 + 3];
      }
      float h = fmaxf(acc, 0.f);
      s_h2[wv][t][u] = A2u * h + B2u;
    }
  }
  __syncthreads();

  float aggv = 0.f;
  if (active && lane < U2) {
    float m = s_h2[wv][0][lane];
    for (int t = 1; t < TT; ++t) m = fmaxf(m, s_h2[wv][t][lane]);
    aggv = m;
  }
  float aggb = __shfl(aggv, lane & 31);
  if (active) {
    int c = lane;
    float vox = -INFINITY;
    for (int t = 0; t < TT; ++t) {
      float mk = s_feat[wv][t * 9 + 7];
      float val = (c < U2) ? s_h2[wv][t][c] : aggb;
      vox = fmaxf(vox, val * mk);
    }
    const int4 cd = *(const int4*)&coord[4 * v];
    long base = ((((long)cd.x * DD + cd.y) * HD + cd.z) * WD + cd.w) * 64;
    atomicAdd(&out[base + c], vox);
  }
}

// ---------------------------------------------------------------------------
extern "C" void kernel_launch(void* const* d_in, const int* in_sizes, int n_in,
                              void* d_out, int out_size, void* d_ws,
                              size_t ws_size, hipStream_t stream) {
  const float* feat = (const float*)d_in[0];
  const float* w1 = (const float*)d_in[1];
  const float* b1 = (const float*)d_in[2];
  const float* g1 = (const float*)d_in[3];
  const float* be1 = (const float*)d_in[4];
  const float* w2 = (const float*)d_in[5];
  const float* b2 = (const float*)d_in[6];
  const float* g2 = (const float*)d_in[7];
  const float* be2 = (const float*)d_in[8];
  const int* coord = (const int*)d_in[9];
  float* out = (float*)d_out;
  float* ws = (float*)d_ws;

  int K = in_sizes[0] / (TT * CIN);
  int P = K * TT;
  float invN = 1.0f / (float)P;
  long n4 = (long)out_size / 4;

  size_t need_bytes =
      ((size_t)WS_H2_OFF + (size_t)K * TT * U2 + (size_t)K * TT) * 4;
  bool store = ws_size >= need_bytes;
  float* h2g = ws + WS_H2_OFF;
  float* maskg = h2g + (size_t)K * TT * U2;

  (void)hipMemsetAsync(d_ws, 0, WS_ZERO_FLOATS * sizeof(float), stream);

  k_stats1<<<512, 256, 0, stream>>>(feat, w1, b1, ws, P);
  k_fin1<<<1, U1, 0, stream>>>(g1, be1, ws, invN);

  int vb = (K + 3) / 4;
  if (store) {
    k_vfe2<true><<<vb, 256, 0, stream>>>(feat, w1, b1, w2, b2, ws, h2g, maskg,
                                         (float4*)out, n4, K);
    k_fin2<<<1, U2, 0, stream>>>(g2, be2, ws, invN);
    k_final<<<vb, 256, 0, stream>>>(h2g, maskg, ws, coord, out, K);
  } else {
    k_vfe2<false><<<vb, 256, 0, stream>>>(feat, w1, b1, w2, b2, ws, nullptr,
                                          nullptr, (float4*)out, n4, K);
    k_fin2<<<1, U2, 0, stream>>>(g2, be2, ws, invN);
    k_vfe_final_recompute<<<vb, 256, 0, stream>>>(feat, w1, b1, w2, b2, coord,
                                                  ws, out, K);
  }
}

// Round 4
// 911.290 us; speedup vs baseline: 1.1222x; 1.0046x over previous
//
#include <hip/hip_runtime.h>
#include <math.h>

#define TT 35
#define DD 10
#define HD 400
#define WD 352
#define CIN 7
#define U1 16
#define U2 32
#define EPSV 1e-5f

// ws float layout
#define WS_SUM1 256   // 32 copies x 16
#define WS_SSQ1 768
#define WS_SUM2 1280  // 16 copies x 32
#define WS_SSQ2 1792
#define NC1 32
#define NC2 16
#define WS_ZERO_FLOATS 2304
#define WS_H2_OFF_FLOATS 4096  // h2 (bf16 frags) starts here
#define MASK_STRIDE 36

typedef __bf16 bf16x8 __attribute__((ext_vector_type(8)));
typedef float f32x4 __attribute__((ext_vector_type(4)));

__device__ inline float bf2f(unsigned short b) {
  unsigned u = ((unsigned)b) << 16;
  return __builtin_bit_cast(float, u);
}
__device__ inline unsigned short f2bf(float x) {
  unsigned u = __builtin_bit_cast(unsigned, x);
  unsigned r = (u + 0x7fff + ((u >> 16) & 1)) >> 16;
  return (unsigned short)r;
}

// ---------------------------------------------------------------------------
// Layer-1 BN statistics (unchanged; ~10us, read-bound on 39MB).
// ---------------------------------------------------------------------------
__global__ __launch_bounds__(256) void k_stats1(
    const float* __restrict__ feat, const float* __restrict__ w1,
    const float* __restrict__ b1, float* __restrict__ ws, int P) {
  __shared__ float s_w1[CIN * U1];
  __shared__ float s_b1[U1];
  __shared__ float s_red[4][2 * U1];

  int tid = threadIdx.x;
  if (tid < CIN * U1) s_w1[tid] = w1[tid];
  if (tid < U1) s_b1[tid] = b1[tid];
  __syncthreads();

  float sum[U1], ssq[U1];
#pragma unroll
  for (int u = 0; u < U1; ++u) { sum[u] = 0.f; ssq[u] = 0.f; }

  int stride = gridDim.x * blockDim.x;
  for (int p = blockIdx.x * blockDim.x + tid; p < P; p += stride) {
    const float* f = feat + (size_t)p * CIN;
    float x[CIN];
#pragma unroll
    for (int c = 0; c < CIN; ++c) x[c] = f[c];
#pragma unroll
    for (int u = 0; u < U1; ++u) {
      float acc = s_b1[u];
#pragma unroll
      for (int c = 0; c < CIN; ++c) acc += x[c] * s_w1[c * U1 + u];
      float h = fmaxf(acc, 0.f);
      sum[u] += h;
      ssq[u] += h * h;
    }
  }

  int lane = tid & 63, wv = tid >> 6;
#pragma unroll
  for (int u = 0; u < U1; ++u) {
    float s = sum[u], q = ssq[u];
    for (int off = 32; off; off >>= 1) {
      s += __shfl_down(s, off);
      q += __shfl_down(q, off);
    }
    if (lane == 0) { s_red[wv][u] = s; s_red[wv][U1 + u] = q; }
  }
  __syncthreads();
  if (tid < 2 * U1) {
    float tot = s_red[0][tid] + s_red[1][tid] + s_red[2][tid] + s_red[3][tid];
    int copy = blockIdx.x & (NC1 - 1);
    int u = tid & (U1 - 1);
    int base = (tid < U1) ? WS_SUM1 : WS_SSQ1;
    atomicAdd(&ws[base + copy * U1 + u], tot);
  }
}

// ---------------------------------------------------------------------------
// Main pass: one wave per voxel, 4 voxels/block.
//  - per-wave fin1 (BN1 affine from ws partials)
//  - stage1 in registers (global feat loads; 16 same-addr lanes merge)
//  - cat -> bf16 LDS (K-interleaved h/agg), stage2 = 6x mfma_16x16x32_bf16
//  - h2 stored bf16 in C-fragment layout (coalesced dwordx2)
//  - layer-2 stats partials -> ws atomics
//  - epilogue: grid-stride zero of out (721MB; overlaps compute)
// ---------------------------------------------------------------------------
__global__ __launch_bounds__(256) void k_vfe2(
    const float* __restrict__ feat, const float* __restrict__ w1,
    const float* __restrict__ b1, const float* __restrict__ g1,
    const float* __restrict__ be1, const float* __restrict__ w2,
    const float* __restrict__ b2, float* __restrict__ ws,
    unsigned short* __restrict__ h2g, float* __restrict__ maskg,
    float4* __restrict__ out4, long n4, int K, float invN) {
  __shared__ unsigned short s_w2b[32 * 40];     // [n][c'] stride 40 (conflict-free)
  __shared__ unsigned short s_catb[4][48][32];  // bf16 cat, rows 64B, pad rows 35-47=0
  __shared__ float s_red[4][64];

  int tid = threadIdx.x;
  int lane = tid & 63, wv = tid >> 6;
  int g = lane >> 4, u = lane & 15;
  int v = blockIdx.x * 4 + wv;
  bool active = (v < K);

  // ---- stage w2 -> bf16, transposed + K-permuted: c'=2i <-> c=i (h half),
  //      c'=2i+1 <-> c=16+i (agg half) ----
  for (int i = tid; i < 32 * 32; i += 256) {
    int n = i >> 5, cp = i & 31;
    int c = (cp & 1) ? (16 + (cp >> 1)) : (cp >> 1);
    s_w2b[n * 40 + cp] = f2bf(w2[c * 32 + n]);
  }
  // ---- zero M-pad rows 35..47 of each wave's cat tile ----
  {
    unsigned* z = (unsigned*)s_catb;
    for (int i = tid; i < 4 * 13 * 16; i += 256) {
      int w = i / 208, rem = i % 208;
      int row = 35 + (rem >> 4), k = rem & 15;
      z[(w * 48 + row) * 16 + k] = 0u;
    }
  }

  // ---- per-lane fin1: BN1 affine for channel u ----
  float s1 = 0.f, q1 = 0.f;
#pragma unroll
  for (int c = 0; c < NC1; ++c) {
    s1 += ws[WS_SUM1 + c * U1 + u];
    q1 += ws[WS_SSQ1 + c * U1 + u];
  }
  float mean1 = s1 * invN;
  float var1 = q1 * invN - mean1 * mean1;
  float A1 = g1[u] / sqrtf(var1 + EPSV);
  float B1 = be1[u] - mean1 * A1;

  // ---- w1 row for channel u in registers ----
  float w1r[CIN];
#pragma unroll
  for (int c = 0; c < CIN; ++c) w1r[c] = w1[c * U1 + u];
  float b1u = b1[u];

  // ---- stage 1: rows t = g + 4j ----
  float h1n[9], mkv[9];
  float aggl = -INFINITY;
  const float* fv = feat + (size_t)v * (TT * CIN);
#pragma unroll
  for (int j = 0; j < 9; ++j) {
    int t = g + 4 * j;
    h1n[j] = -INFINITY;
    mkv[j] = 0.f;
    if (active && t < TT) {
      const float* fr = fv + t * CIN;
      float x0 = fr[0], x1 = fr[1], x2 = fr[2], x3 = fr[3];
      float x4 = fr[4], x5 = fr[5], x6 = fr[6];
      float m = fmaxf(fmaxf(fmaxf(x0, x1), fmaxf(x2, x3)),
                      fmaxf(fmaxf(x4, x5), x6));
      float mk = (m != 0.f) ? 1.f : 0.f;
      float acc = b1u + x0 * w1r[0] + x1 * w1r[1] + x2 * w1r[2] +
                  x3 * w1r[3] + x4 * w1r[4] + x5 * w1r[5] + x6 * w1r[6];
      float h = fmaxf(acc, 0.f);
      h1n[j] = A1 * h + B1;
      mkv[j] = mk;
      if (u == 0) maskg[(size_t)v * MASK_STRIDE + t] = mk;
      aggl = fmaxf(aggl, h1n[j]);
    }
  }
  // agg1 = max over all t (unmasked) — reduce across the 4 g-groups
  aggl = fmaxf(aggl, __shfl_xor(aggl, 16));
  aggl = fmaxf(aggl, __shfl_xor(aggl, 32));

  // ---- write cat rows: packed (h*mk, agg*mk) bf16x2 at cols (2u, 2u+1) ----
#pragma unroll
  for (int j = 0; j < 9; ++j) {
    int t = g + 4 * j;
    if (active && t < TT) {
      unsigned pk = (unsigned)f2bf(h1n[j] * mkv[j]) |
                    ((unsigned)f2bf(aggl * mkv[j]) << 16);
      *(unsigned*)&s_catb[wv][t][2 * u] = pk;
    }
  }
  __syncthreads();  // covers s_w2b staging + pad-row zeroing (cat rows are own-wave)

  // ---- stage 2: 6x MFMA (M-tiles 0..2, N-tiles 0..1) ----
  f32x4 acc[2][3];
#pragma unroll
  for (int nt = 0; nt < 2; ++nt)
#pragma unroll
    for (int mt = 0; mt < 3; ++mt) acc[nt][mt] = (f32x4)(0.f);

  bf16x8 bfr[2];
#pragma unroll
  for (int nt = 0; nt < 2; ++nt) {
    uint4 raw = *(const uint4*)&s_w2b[(nt * 16 + u) * 40 + g * 8];
    bfr[nt] = __builtin_bit_cast(bf16x8, raw);
  }
#pragma unroll
  for (int mt = 0; mt < 3; ++mt) {
    uint4 raw = *(const uint4*)&s_catb[wv][mt * 16 + u][g * 8];
    bf16x8 afr = __builtin_bit_cast(bf16x8, raw);
#pragma unroll
    for (int nt = 0; nt < 2; ++nt)
      acc[nt][mt] =
          __builtin_amdgcn_mfma_f32_16x16x32_bf16(afr, bfr[nt], acc[nt][mt], 0, 0, 0);
  }

  // ---- bias+relu, layer-2 stats, h2 store (C-frag layout, bf16) ----
  float b2c[2] = {b2[u], b2[16 + u]};
  float sum[2] = {0.f, 0.f}, ssq[2] = {0.f, 0.f};
#pragma unroll
  for (int nt = 0; nt < 2; ++nt) {
#pragma unroll
    for (int mt = 0; mt < 3; ++mt) {
      unsigned pk[2];
      float hv[4];
#pragma unroll
      for (int r = 0; r < 4; ++r) {
        int row = mt * 16 + g * 4 + r;
        float h = fmaxf(acc[nt][mt][r] + b2c[nt], 0.f);
        hv[r] = h;
        if (row < TT) {
          sum[nt] += h;
          ssq[nt] += h * h;
        }
      }
      pk[0] = (unsigned)f2bf(hv[0]) | ((unsigned)f2bf(hv[1]) << 16);
      pk[1] = (unsigned)f2bf(hv[2]) | ((unsigned)f2bf(hv[3]) << 16);
      if (active) {
        uint2 st = make_uint2(pk[0], pk[1]);
        *(uint2*)&h2g[((size_t)v * 6 + nt * 3 + mt) * 256 + lane * 4] = st;
      }
    }
  }

  // reduce stats across g-groups, then cross-wave, then ws atomics
#pragma unroll
  for (int nt = 0; nt < 2; ++nt) {
    sum[nt] += __shfl_xor(sum[nt], 16);
    sum[nt] += __shfl_xor(sum[nt], 32);
    ssq[nt] += __shfl_xor(ssq[nt], 16);
    ssq[nt] += __shfl_xor(ssq[nt], 32);
  }
  float contrib = 0.f;
  if (active) {
    contrib = (g == 0) ? sum[0] : (g == 1) ? sum[1] : (g == 2) ? ssq[0] : ssq[1];
  }
  s_red[wv][(g & 1) * 16 + u + (g >> 1) * 32] = contrib;
  __syncthreads();
  if (tid < 64) {
    float tot = s_red[0][tid] + s_red[1][tid] + s_red[2][tid] + s_red[3][tid];
    int copy = blockIdx.x & (NC2 - 1);
    int ch = tid & 31;
    int base = (tid < 32) ? WS_SUM2 : WS_SSQ2;
    atomicAdd(&ws[base + copy * U2 + ch], tot);
  }

  // ---- epilogue: zero the output tensor (fire-and-forget) ----
  long gtid = (long)blockIdx.x * 256 + tid;
  long gstride = (long)gridDim.x * 256;
  float4 zz = make_float4(0.f, 0.f, 0.f, 0.f);
  for (long i = gtid; i < n4; i += gstride) out4[i] = zz;
}

// ---------------------------------------------------------------------------
// Final pass: per-wave fin2, read h2 fragments + mask, BN affine, agg2 +
// voxelwise max via butterfly, coalesced atomicAdd scatter.
// ---------------------------------------------------------------------------
__global__ __launch_bounds__(256) void k_final(
    const unsigned short* __restrict__ h2g, const float* __restrict__ maskg,
    const float* __restrict__ ws, const float* __restrict__ g2,
    const float* __restrict__ be2, const int* __restrict__ coord,
    float* __restrict__ out, int K, float invN) {
  int tid = threadIdx.x;
  int lane = tid & 63, wv = tid >> 6;
  int g = lane >> 4, u = lane & 15;
  int v = blockIdx.x * 4 + wv;
  if (v >= K) return;

  // fin2 for ch0=u, ch1=16+u
  float A2[2], B2[2];
#pragma unroll
  for (int h = 0; h < 2; ++h) {
    int ch = h * 16 + u;
    float s = 0.f, q = 0.f;
#pragma unroll
    for (int c = 0; c < NC2; ++c) {
      s += ws[WS_SUM2 + c * U2 + ch];
      q += ws[WS_SSQ2 + c * U2 + ch];
    }
    float mean = s * invN;
    float var = q * invN - mean * mean;
    float A = g2[ch] / sqrtf(var + EPSV);
    A2[h] = A;
    B2[h] = be2[ch] - mean * A;
  }

  float vox[2] = {-INFINITY, -INFINITY};
  float agg[2] = {-INFINITY, -INFINITY};
  float cnt = 0.f;
#pragma unroll
  for (int mt = 0; mt < 3; ++mt) {
    const float4 mk4 = *(const float4*)&maskg[(size_t)v * MASK_STRIDE + mt * 16 + g * 4];
    float mk[4] = {mk4.x, mk4.y, mk4.z, mk4.w};
#pragma unroll
    for (int nt = 0; nt < 2; ++nt) {
      uint2 raw = *(const uint2*)&h2g[((size_t)v * 6 + nt * 3 + mt) * 256 + lane * 4];
      unsigned short e[4] = {(unsigned short)(raw.x & 0xffff),
                             (unsigned short)(raw.x >> 16),
                             (unsigned short)(raw.y & 0xffff),
                             (unsigned short)(raw.y >> 16)};
#pragma unroll
      for (int r = 0; r < 4; ++r) {
        int row = mt * 16 + g * 4 + r;
        if (row < TT) {
          float hn = A2[nt] * bf2f(e[r]) + B2[nt];
          agg[nt] = fmaxf(agg[nt], hn);
          vox[nt] = fmaxf(vox[nt], hn * mk[r]);
          if (nt == 0) cnt += mk[r];
        }
      }
    }
  }
#pragma unroll
  for (int nt = 0; nt < 2; ++nt) {
    vox[nt] = fmaxf(vox[nt], __shfl_xor(vox[nt], 16));
    vox[nt] = fmaxf(vox[nt], __shfl_xor(vox[nt], 32));
    agg[nt] = fmaxf(agg[nt], __shfl_xor(agg[nt], 16));
    agg[nt] = fmaxf(agg[nt], __shfl_xor(agg[nt], 32));
  }
  cnt += __shfl_xor(cnt, 16);
  cnt += __shfl_xor(cnt, 32);

  float val;
  if (lane < 32) {
    val = (lane < 16) ? vox[0] : vox[1];
  } else {
    float a = (lane < 48) ? agg[0] : agg[1];
    val = (cnt > 0.5f) ? ((cnt < TT - 0.5f) ? fmaxf(a, 0.f) : a) : 0.f;
  }
  const int4 cd = *(const int4*)&coord[4 * v];
  long base = ((((long)cd.x * DD + cd.y) * HD + cd.z) * WD + cd.w) * 64;
  atomicAdd(&out[base + lane], val);
}

// ---------------------------------------------------------------------------
extern "C" void kernel_launch(void* const* d_in, const int* in_sizes, int n_in,
                              void* d_out, int out_size, void* d_ws,
                              size_t ws_size, hipStream_t stream) {
  const float* feat = (const float*)d_in[0];
  const float* w1 = (const float*)d_in[1];
  const float* b1 = (const float*)d_in[2];
  const float* g1 = (const float*)d_in[3];
  const float* be1 = (const float*)d_in[4];
  const float* w2 = (const float*)d_in[5];
  const float* b2 = (const float*)d_in[6];
  const float* g2 = (const float*)d_in[7];
  const float* be2 = (const float*)d_in[8];
  const int* coord = (const int*)d_in[9];
  float* out = (float*)d_out;
  float* ws = (float*)d_ws;

  int K = in_sizes[0] / (TT * CIN);
  int P = K * TT;
  float invN = 1.0f / (float)P;
  long n4 = (long)out_size / 4;

  unsigned short* h2g = (unsigned short*)(ws + WS_H2_OFF_FLOATS);
  float* maskg = (float*)(h2g + (size_t)K * 6 * 256);

  (void)hipMemsetAsync(d_ws, 0, WS_ZERO_FLOATS * sizeof(float), stream);

  k_stats1<<<512, 256, 0, stream>>>(feat, w1, b1, ws, P);

  int vb = (K + 3) / 4;
  k_vfe2<<<vb, 256, 0, stream>>>(feat, w1, b1, g1, be1, w2, b2, ws, h2g, maskg,
                                 (float4*)out, n4, K, invN);
  k_final<<<vb, 256, 0, stream>>>(h2g, maskg, ws, g2, be2, coord, out, K, invN);
}

// Round 5
// 849.890 us; speedup vs baseline: 1.2032x; 1.0722x over previous
//
#include <hip/hip_runtime.h>
#include <math.h>

#define TT 35
#define DD 10
#define HD 400
#define WD 352
#define CIN 7
#define U1 16
#define U2 32
#define EPSV 1e-5f

// ws float layout
#define WS_SUM1 256   // 32 copies x 16
#define WS_SSQ1 768
#define WS_SUM2 1280  // 16 copies x 32
#define WS_SSQ2 1792
#define NC1 32
#define NC2 16
#define WS_ZERO_FLOATS 2304
#define WS_SUM_OFF 4096  // per-voxel channel summaries start here

typedef __bf16 bf16x8 __attribute__((ext_vector_type(8)));
typedef float f32x4 __attribute__((ext_vector_type(4)));

__device__ inline unsigned short f2bf(float x) {
  unsigned u = __builtin_bit_cast(unsigned, x);
  unsigned r = (u + 0x7fff + ((u >> 16) & 1)) >> 16;
  return (unsigned short)r;
}

// ---------------------------------------------------------------------------
// Layer-1 BN statistics (~12us, read-bound on 39MB).
// ---------------------------------------------------------------------------
__global__ __launch_bounds__(256) void k_stats1(
    const float* __restrict__ feat, const float* __restrict__ w1,
    const float* __restrict__ b1, float* __restrict__ ws, int P) {
  __shared__ float s_w1[CIN * U1];
  __shared__ float s_b1[U1];
  __shared__ float s_red[4][2 * U1];

  int tid = threadIdx.x;
  if (tid < CIN * U1) s_w1[tid] = w1[tid];
  if (tid < U1) s_b1[tid] = b1[tid];
  __syncthreads();

  float sum[U1], ssq[U1];
#pragma unroll
  for (int u = 0; u < U1; ++u) { sum[u] = 0.f; ssq[u] = 0.f; }

  int stride = gridDim.x * blockDim.x;
  for (int p = blockIdx.x * blockDim.x + tid; p < P; p += stride) {
    const float* f = feat + (size_t)p * CIN;
    float x[CIN];
#pragma unroll
    for (int c = 0; c < CIN; ++c) x[c] = f[c];
#pragma unroll
    for (int u = 0; u < U1; ++u) {
      float acc = s_b1[u];
#pragma unroll
      for (int c = 0; c < CIN; ++c) acc += x[c] * s_w1[c * U1 + u];
      float h = fmaxf(acc, 0.f);
      sum[u] += h;
      ssq[u] += h * h;
    }
  }

  int lane = tid & 63, wv = tid >> 6;
#pragma unroll
  for (int u = 0; u < U1; ++u) {
    float s = sum[u], q = ssq[u];
    for (int off = 32; off; off >>= 1) {
      s += __shfl_down(s, off);
      q += __shfl_down(q, off);
    }
    if (lane == 0) { s_red[wv][u] = s; s_red[wv][U1 + u] = q; }
  }
  __syncthreads();
  if (tid < 2 * U1) {
    float tot = s_red[0][tid] + s_red[1][tid] + s_red[2][tid] + s_red[3][tid];
    int copy = blockIdx.x & (NC1 - 1);
    int u = tid & (U1 - 1);
    int base = (tid < U1) ? WS_SUM1 : WS_SSQ1;
    atomicAdd(&ws[base + copy * U1 + u], tot);
  }
}

// ---------------------------------------------------------------------------
// Main pass: one wave per voxel, 4 voxels/block.
//  - per-wave fin1; stage1 in registers; cat -> bf16 LDS; 6x MFMA
//  - per-(voxel,channel) summaries {maxm,minm,maxa,mina} (fp32) + cnt
//  - layer-2 stats partials -> ws atomics
//  - epilogue: grid-stride zero of out (721MB; overlaps across blocks)
// ---------------------------------------------------------------------------
__global__ __launch_bounds__(256) void k_vfe2(
    const float* __restrict__ feat, const float* __restrict__ w1,
    const float* __restrict__ b1, const float* __restrict__ g1,
    const float* __restrict__ be1, const float* __restrict__ w2,
    const float* __restrict__ b2, float* __restrict__ ws,
    float* __restrict__ sumg, float* __restrict__ cntg,
    float4* __restrict__ out4, long n4, int K, float invN) {
  __shared__ unsigned short s_w2b[32 * 40];     // [n][c'] stride 40
  __shared__ unsigned short s_catb[4][48][32];  // bf16 cat; pad rows 35-47 = 0
  __shared__ float s_mk[4][40];                 // mask per row
  __shared__ float s_red[4][64];

  int tid = threadIdx.x;
  int lane = tid & 63, wv = tid >> 6;
  int g = lane >> 4, u = lane & 15;
  int v = blockIdx.x * 4 + wv;
  bool active = (v < K);

  // ---- stage w2 -> bf16, transposed + K-permuted (c'=2i<->c=i, c'=2i+1<->c=16+i)
  for (int i = tid; i < 32 * 32; i += 256) {
    int n = i >> 5, cp = i & 31;
    int c = (cp & 1) ? (16 + (cp >> 1)) : (cp >> 1);
    s_w2b[n * 40 + cp] = f2bf(w2[c * 32 + n]);
  }
  // ---- zero M-pad rows 35..47 of each wave's cat tile ----
  {
    unsigned* z = (unsigned*)s_catb;
    for (int i = tid; i < 4 * 13 * 16; i += 256) {
      int w = i / 208, rem = i % 208;
      int row = 35 + (rem >> 4), k = rem & 15;
      z[(w * 48 + row) * 16 + k] = 0u;
    }
  }

  // ---- per-lane fin1: BN1 affine for channel u ----
  float s1 = 0.f, q1 = 0.f;
#pragma unroll
  for (int c = 0; c < NC1; ++c) {
    s1 += ws[WS_SUM1 + c * U1 + u];
    q1 += ws[WS_SSQ1 + c * U1 + u];
  }
  float mean1 = s1 * invN;
  float var1 = q1 * invN - mean1 * mean1;
  float A1 = g1[u] / sqrtf(var1 + EPSV);
  float B1 = be1[u] - mean1 * A1;

  float w1r[CIN];
#pragma unroll
  for (int c = 0; c < CIN; ++c) w1r[c] = w1[c * U1 + u];
  float b1u = b1[u];

  // ---- stage 1: rows t = g + 4j ----
  float h1n[9], mkv[9];
  float aggl = -INFINITY;
  float cntl = 0.f;
  const float* fv = feat + (size_t)v * (TT * CIN);
#pragma unroll
  for (int j = 0; j < 9; ++j) {
    int t = g + 4 * j;
    h1n[j] = -INFINITY;
    mkv[j] = 0.f;
    if (active && t < TT) {
      const float* fr = fv + t * CIN;
      float x0 = fr[0], x1 = fr[1], x2 = fr[2], x3 = fr[3];
      float x4 = fr[4], x5 = fr[5], x6 = fr[6];
      float m = fmaxf(fmaxf(fmaxf(x0, x1), fmaxf(x2, x3)),
                      fmaxf(fmaxf(x4, x5), x6));
      float mk = (m != 0.f) ? 1.f : 0.f;
      float acc = b1u + x0 * w1r[0] + x1 * w1r[1] + x2 * w1r[2] +
                  x3 * w1r[3] + x4 * w1r[4] + x5 * w1r[5] + x6 * w1r[6];
      float h = fmaxf(acc, 0.f);
      h1n[j] = A1 * h + B1;
      mkv[j] = mk;
      cntl += mk;
      if (u == 0) s_mk[wv][t] = mk;
      aggl = fmaxf(aggl, h1n[j]);
    }
  }
  // agg1 / cnt across the 4 g-groups (u-lanes within a group are identical)
  aggl = fmaxf(aggl, __shfl_xor(aggl, 16));
  aggl = fmaxf(aggl, __shfl_xor(aggl, 32));
  cntl += __shfl_xor(cntl, 16);
  cntl += __shfl_xor(cntl, 32);
  if (active && lane == 0) cntg[v] = cntl;

  // ---- write cat rows: packed (h*mk, agg*mk) bf16x2 at cols (2u, 2u+1) ----
#pragma unroll
  for (int j = 0; j < 9; ++j) {
    int t = g + 4 * j;
    if (active && t < TT) {
      unsigned pk = (unsigned)f2bf(h1n[j] * mkv[j]) |
                    ((unsigned)f2bf(aggl * mkv[j]) << 16);
      *(unsigned*)&s_catb[wv][t][2 * u] = pk;
    }
  }
  __syncthreads();

  // ---- stage 2: 6x MFMA ----
  f32x4 acc[2][3];
#pragma unroll
  for (int nt = 0; nt < 2; ++nt)
#pragma unroll
    for (int mt = 0; mt < 3; ++mt) acc[nt][mt] = (f32x4)(0.f);

  bf16x8 bfr[2];
#pragma unroll
  for (int nt = 0; nt < 2; ++nt) {
    uint4 raw = *(const uint4*)&s_w2b[(nt * 16 + u) * 40 + g * 8];
    bfr[nt] = __builtin_bit_cast(bf16x8, raw);
  }
#pragma unroll
  for (int mt = 0; mt < 3; ++mt) {
    uint4 raw = *(const uint4*)&s_catb[wv][mt * 16 + u][g * 8];
    bf16x8 afr = __builtin_bit_cast(bf16x8, raw);
#pragma unroll
    for (int nt = 0; nt < 2; ++nt)
      acc[nt][mt] =
          __builtin_amdgcn_mfma_f32_16x16x32_bf16(afr, bfr[nt], acc[nt][mt], 0, 0, 0);
  }

  // ---- bias+relu, layer-2 stats, channel summaries ----
  float b2c[2] = {b2[u], b2[16 + u]};
  float sum[2] = {0.f, 0.f}, ssq[2] = {0.f, 0.f};
  float maxm[2] = {-INFINITY, -INFINITY}, minm[2] = {INFINITY, INFINITY};
  float maxa[2] = {-INFINITY, -INFINITY}, mina[2] = {INFINITY, INFINITY};
#pragma unroll
  for (int nt = 0; nt < 2; ++nt) {
#pragma unroll
    for (int mt = 0; mt < 3; ++mt) {
#pragma unroll
      for (int r = 0; r < 4; ++r) {
        int row = mt * 16 + g * 4 + r;
        if (row < TT) {
          float h = fmaxf(acc[nt][mt][r] + b2c[nt], 0.f);
          sum[nt] += h;
          ssq[nt] += h * h;
          maxa[nt] = fmaxf(maxa[nt], h);
          mina[nt] = fminf(mina[nt], h);
          float mk = s_mk[wv][row];
          if (mk != 0.f) {
            maxm[nt] = fmaxf(maxm[nt], h);
            minm[nt] = fminf(minm[nt], h);
          }
        }
      }
    }
  }

  // reduce all summaries + stats across g-groups
#pragma unroll
  for (int nt = 0; nt < 2; ++nt) {
    sum[nt] += __shfl_xor(sum[nt], 16);
    sum[nt] += __shfl_xor(sum[nt], 32);
    ssq[nt] += __shfl_xor(ssq[nt], 16);
    ssq[nt] += __shfl_xor(ssq[nt], 32);
    maxa[nt] = fmaxf(maxa[nt], __shfl_xor(maxa[nt], 16));
    maxa[nt] = fmaxf(maxa[nt], __shfl_xor(maxa[nt], 32));
    mina[nt] = fminf(mina[nt], __shfl_xor(mina[nt], 16));
    mina[nt] = fminf(mina[nt], __shfl_xor(mina[nt], 32));
    maxm[nt] = fmaxf(maxm[nt], __shfl_xor(maxm[nt], 16));
    maxm[nt] = fmaxf(maxm[nt], __shfl_xor(maxm[nt], 32));
    minm[nt] = fminf(minm[nt], __shfl_xor(minm[nt], 16));
    minm[nt] = fminf(minm[nt], __shfl_xor(minm[nt], 32));
  }
  if (active && g == 0) {
#pragma unroll
    for (int nt = 0; nt < 2; ++nt) {
      float4 sm = make_float4(maxm[nt], minm[nt], maxa[nt], mina[nt]);
      *(float4*)&sumg[(size_t)v * 128 + (nt * 16 + u) * 4] = sm;
    }
  }

  float contrib = 0.f;
  if (active) {
    contrib = (g == 0) ? sum[0] : (g == 1) ? sum[1] : (g == 2) ? ssq[0] : ssq[1];
  }
  s_red[wv][(g & 1) * 16 + u + (g >> 1) * 32] = contrib;
  __syncthreads();
  if (tid < 64) {
    float tot = s_red[0][tid] + s_red[1][tid] + s_red[2][tid] + s_red[3][tid];
    int copy = blockIdx.x & (NC2 - 1);
    int ch = tid & 31;
    int base = (tid < 32) ? WS_SUM2 : WS_SSQ2;
    atomicAdd(&ws[base + copy * U2 + ch], tot);
  }

  // ---- epilogue: zero the output tensor ----
  long gtid = (long)blockIdx.x * 256 + tid;
  long gstride = (long)gridDim.x * 256;
  float4 zz = make_float4(0.f, 0.f, 0.f, 0.f);
  for (long i = gtid; i < n4; i += gstride) out4[i] = zz;
}

// ---------------------------------------------------------------------------
// Final pass: 8 voxels/block, thread = (voxel, channel). fin2 per thread,
// finalize from summaries, 2 coalesced atomicAdds.
// ---------------------------------------------------------------------------
__global__ __launch_bounds__(256) void k_final(
    const float* __restrict__ sumg, const float* __restrict__ cntg,
    const float* __restrict__ ws, const float* __restrict__ g2,
    const float* __restrict__ be2, const int* __restrict__ coord,
    float* __restrict__ out, int K, float invN) {
  int tid = threadIdx.x;
  int v = blockIdx.x * 8 + (tid >> 5);
  int ch = tid & 31;
  if (v >= K) return;

  float s = 0.f, q = 0.f;
#pragma unroll
  for (int c = 0; c < NC2; ++c) {
    s += ws[WS_SUM2 + c * U2 + ch];
    q += ws[WS_SSQ2 + c * U2 + ch];
  }
  float mean = s * invN;
  float var = q * invN - mean * mean;
  float A2 = g2[ch] / sqrtf(var + EPSV);
  float B2 = be2[ch] - mean * A2;

  float4 sm = *(const float4*)&sumg[(size_t)v * 128 + ch * 4];
  float cnt = cntg[v];

  float hm = (A2 >= 0.f) ? (A2 * sm.x + B2) : (A2 * sm.y + B2);
  float ag = (A2 >= 0.f) ? (A2 * sm.z + B2) : (A2 * sm.w + B2);
  float voxr = (cnt < 0.5f) ? 0.f : ((cnt > TT - 0.5f) ? hm : fmaxf(hm, 0.f));
  float voxa = (cnt < 0.5f) ? 0.f : ((cnt > TT - 0.5f) ? ag : fmaxf(ag, 0.f));

  const int4 cd = *(const int4*)&coord[4 * v];
  long base = ((((long)cd.x * DD + cd.y) * HD + cd.z) * WD + cd.w) * 64;
  atomicAdd(&out[base + ch], voxr);
  atomicAdd(&out[base + 32 + ch], voxa);
}

// ---------------------------------------------------------------------------
extern "C" void kernel_launch(void* const* d_in, const int* in_sizes, int n_in,
                              void* d_out, int out_size, void* d_ws,
                              size_t ws_size, hipStream_t stream) {
  const float* feat = (const float*)d_in[0];
  const float* w1 = (const float*)d_in[1];
  const float* b1 = (const float*)d_in[2];
  const float* g1 = (const float*)d_in[3];
  const float* be1 = (const float*)d_in[4];
  const float* w2 = (const float*)d_in[5];
  const float* b2 = (const float*)d_in[6];
  const float* g2 = (const float*)d_in[7];
  const float* be2 = (const float*)d_in[8];
  const int* coord = (const int*)d_in[9];
  float* out = (float*)d_out;
  float* ws = (float*)d_ws;

  int K = in_sizes[0] / (TT * CIN);
  int P = K * TT;
  float invN = 1.0f / (float)P;
  long n4 = (long)out_size / 4;

  float* sumg = ws + WS_SUM_OFF;
  float* cntg = sumg + (size_t)K * 128;

  (void)hipMemsetAsync(d_ws, 0, WS_ZERO_FLOATS * sizeof(float), stream);

  k_stats1<<<512, 256, 0, stream>>>(feat, w1, b1, ws, P);

  int vb = (K + 3) / 4;
  k_vfe2<<<vb, 256, 0, stream>>>(feat, w1, b1, g1, be1, w2, b2, ws, sumg, cntg,
                                 (float4*)out, n4, K, invN);
  k_final<<<(K + 7) / 8, 256, 0, stream>>>(sumg, cntg, ws, g2, be2, coord, out,
                                           K, invN);
}